// Round 1
// baseline (3835.898 us; speedup 1.0000x reference)
//
#include <hip/hip_runtime.h>
#include <hip/hip_bf16.h>

#define F_IN 512
#define C_DIM 64

// ---------------- degree histogram ----------------
__global__ void deg_kernel(const int* __restrict__ col, int* __restrict__ deg, int E) {
    int i = blockIdx.x * blockDim.x + threadIdx.x;
    if (i < E) atomicAdd(&deg[col[i]], 1);
}

// ---------------- dinv ----------------
__global__ void dinv_kernel(const int* __restrict__ deg, float* __restrict__ dinv, int N) {
    int i = blockIdx.x * blockDim.x + threadIdx.x;
    if (i < N) {
        int d = deg[i];
        dinv[i] = (d > 0) ? (1.0f / sqrtf((float)d)) : 1.0f;
    }
}

// ---------------- scan (3 kernels) ----------------
__global__ void scan1(const int* __restrict__ deg, int* __restrict__ rowptr,
                      int* __restrict__ bsum, int N) {
    __shared__ int tmp[1024];
    int t = threadIdx.x;
    int gid = blockIdx.x * 1024 + t;
    int v = (gid < N) ? deg[gid] : 0;
    tmp[t] = v;
    __syncthreads();
    for (int off = 1; off < 1024; off <<= 1) {
        int u = (t >= off) ? tmp[t - off] : 0;
        __syncthreads();
        tmp[t] += u;
        __syncthreads();
    }
    if (gid < N) rowptr[gid] = tmp[t] - v;   // exclusive within block
    if (t == 1023) bsum[blockIdx.x] = tmp[1023];
}

__global__ void scan2(int* __restrict__ bs, int nb) {
    __shared__ int tmp[1024];
    int t = threadIdx.x;
    int v = (t < nb) ? bs[t] : 0;
    tmp[t] = v;
    __syncthreads();
    for (int off = 1; off < 1024; off <<= 1) {
        int u = (t >= off) ? tmp[t - off] : 0;
        __syncthreads();
        tmp[t] += u;
        __syncthreads();
    }
    if (t < nb) bs[t] = tmp[t] - v;          // exclusive
}

__global__ void scan3(int* __restrict__ rowptr, const int* __restrict__ bs, int E, int N) {
    int gid = blockIdx.x * 1024 + threadIdx.x;
    if (gid < N) rowptr[gid] += bs[blockIdx.x];
    if (gid == 0) rowptr[N] = E;
}

// ---------------- CSR scatter ----------------
__global__ void scatter_kernel(const int* __restrict__ row, const int* __restrict__ col,
                               const float* __restrict__ dinv, const int* __restrict__ rowptr,
                               int* __restrict__ cnt, int* __restrict__ srcv,
                               float* __restrict__ normv, int E) {
    int i = blockIdx.x * blockDim.x + threadIdx.x;
    if (i >= E) return;
    int r = row[i];
    int c = col[i];
    int pos = rowptr[c] + atomicAdd(&cnt[c], 1);
    srcv[pos] = r;
    normv[pos] = dinv[r] * dinv[c];
}

// ---------------- GEMM: h = x@W + b ; ret = h * (1 * mf[0][c]) ----------------
__global__ void gemm_kernel(const float* __restrict__ x, const float* __restrict__ W,
                            const float* __restrict__ b, const float* __restrict__ mf,
                            float* __restrict__ h, float* __restrict__ ret, int N) {
    __shared__ float4 xs4[4 * F_IN / 4];          // 4 rows x 512 floats
    const float* xs = (const float*)xs4;
    int rowblk = blockIdx.x * 4;
    // cooperative stage: 512 float4, 256 threads -> 2 each
    for (int i = threadIdx.x; i < 4 * F_IN / 4; i += 256) {
        int r = i >> 7;            // 128 float4 per row
        int kk = i & 127;
        int gr = rowblk + r;
        float4 v = make_float4(0.f, 0.f, 0.f, 0.f);
        if (gr < N) v = ((const float4*)x)[(size_t)gr * (F_IN / 4) + kk];
        xs4[i] = v;
    }
    __syncthreads();
    int wv = threadIdx.x >> 6;
    int c  = threadIdx.x & 63;
    int n = rowblk + wv;
    if (n >= N) return;
    float acc = b[c];
    const float* xr = xs + wv * F_IN;
    #pragma unroll 8
    for (int k = 0; k < F_IN; ++k)
        acc = fmaf(xr[k], W[k * C_DIM + c], acc);
    h[(size_t)n * C_DIM + c] = acc;
    ret[(size_t)n * C_DIM + c] = acc * mf[c];     // coef0 = 1, mf[0][c]
}

// ---------------- propagation + polynomial accumulate ----------------
// mode 0: P1 = prop(Hin);  mode 1: Pn = 2*prop(Hin) - Pout(old)
__global__ void prop_kernel(const int* __restrict__ rowptr, const int* __restrict__ srcv,
                            const float* __restrict__ normv, const float* __restrict__ Hin,
                            float* __restrict__ Pout, float* __restrict__ ret,
                            const float* __restrict__ lap, const float* __restrict__ mf,
                            int k, int mode, int N) {
    int wid = (blockIdx.x * blockDim.x + threadIdx.x) >> 6;
    int c = threadIdx.x & 63;
    if (wid >= N) return;
    int beg = rowptr[wid];
    int end = rowptr[wid + 1];
    float acc = 0.f;
    for (int e = beg; e < end; ++e) {
        int s = srcv[e];
        float w = normv[e];
        acc = fmaf(w, Hin[(size_t)s * C_DIM + c], acc);
    }
    size_t idx = (size_t)wid * C_DIM + c;
    float p = (mode == 0) ? acc : (2.0f * acc - Pout[idx]);
    Pout[idx] = p;
    float wk = lap[k - 1] * mf[k * C_DIM + c];
    ret[idx] += wk * p;
}

// ---------------- log softmax (wave per row) ----------------
__global__ void lsm_kernel(float* __restrict__ ret, int N) {
    int wid = (blockIdx.x * blockDim.x + threadIdx.x) >> 6;
    int c = threadIdx.x & 63;
    if (wid >= N) return;
    size_t idx = (size_t)wid * C_DIM + c;
    float v = ret[idx];
    float m = v;
    for (int off = 32; off; off >>= 1) m = fmaxf(m, __shfl_xor(m, off, 64));
    float ex = __expf(v - m);
    float s = ex;
    for (int off = 32; off; off >>= 1) s += __shfl_xor(s, off, 64);
    ret[idx] = (v - m) - logf(s);
}

extern "C" void kernel_launch(void* const* d_in, const int* in_sizes, int n_in,
                              void* d_out, int out_size, void* d_ws, size_t ws_size,
                              hipStream_t stream) {
    const float* x   = (const float*)d_in[0];
    const int*   ei  = (const int*)d_in[1];
    const float* W   = (const float*)d_in[2];
    const float* b   = (const float*)d_in[3];
    const float* lap = (const float*)d_in[4];
    const float* mf  = (const float*)d_in[5];
    float* ret = (float*)d_out;

    const int C = in_sizes[3];            // 64
    const int FIN = in_sizes[2] / C;      // 512
    const int N = in_sizes[0] / FIN;      // 100000
    const int E = in_sizes[1] / 2;        // 3200000
    const int K = in_sizes[4] - 1;        // 10
    const int* rowi = ei;                 // edge_index[0]
    const int* coli = ei + E;             // edge_index[1]

    // workspace layout (256B aligned)
    char* w = (char*)d_ws;
    auto alloc = [&](size_t bytes) {
        void* p = (void*)w;
        w += (bytes + 255) & ~(size_t)255;
        return p;
    };
    int*   deg    = (int*)alloc((size_t)N * 4);
    int*   cnt    = (int*)alloc((size_t)N * 4);
    int*   rowptr = (int*)alloc((size_t)(N + 1) * 4);
    int*   bsum   = (int*)alloc(4096);
    float* dinv   = (float*)alloc((size_t)N * 4);
    int*   srcv   = (int*)alloc((size_t)E * 4);
    float* normv  = (float*)alloc((size_t)E * 4);
    float* h      = (float*)alloc((size_t)N * C_DIM * 4);
    float* pbuf   = (float*)alloc((size_t)N * C_DIM * 4);

    hipMemsetAsync(deg, 0, (size_t)N * 4, stream);
    hipMemsetAsync(cnt, 0, (size_t)N * 4, stream);

    deg_kernel<<<(E + 255) / 256, 256, 0, stream>>>(coli, deg, E);
    dinv_kernel<<<(N + 255) / 256, 256, 0, stream>>>(deg, dinv, N);

    int nb = (N + 1023) / 1024;
    scan1<<<nb, 1024, 0, stream>>>(deg, rowptr, bsum, N);
    scan2<<<1, 1024, 0, stream>>>(bsum, nb);
    scan3<<<nb, 1024, 0, stream>>>(rowptr, bsum, E, N);

    scatter_kernel<<<(E + 255) / 256, 256, 0, stream>>>(rowi, coli, dinv, rowptr, cnt,
                                                        srcv, normv, E);

    gemm_kernel<<<(N + 3) / 4, 256, 0, stream>>>(x, W, b, mf, h, ret, N);

    // P0 = h (in ret already). P1 = prop(h) into pbuf.
    float* prev2 = h;
    float* prev1 = pbuf;
    prop_kernel<<<(N + 3) / 4, 256, 0, stream>>>(rowptr, srcv, normv, h, pbuf, ret,
                                                 lap, mf, 1, 0, N);
    for (int k = 2; k <= K; ++k) {
        prop_kernel<<<(N + 3) / 4, 256, 0, stream>>>(rowptr, srcv, normv, prev1, prev2, ret,
                                                     lap, mf, k, 1, N);
        float* t = prev2;   // now holds P_k
        prev2 = prev1;
        prev1 = t;
    }

    lsm_kernel<<<(N + 3) / 4, 256, 0, stream>>>(ret, N);
}

// Round 2
// 1992.460 us; speedup vs baseline: 1.9252x; 1.9252x over previous
//
#include <hip/hip_runtime.h>
#include <hip/hip_bf16.h>

#define F_IN 512
#define C_DIM 64

// ---------------- degree histogram ----------------
__global__ void deg_kernel(const int* __restrict__ col, int* __restrict__ deg, int E) {
    int i = blockIdx.x * blockDim.x + threadIdx.x;
    if (i < E) atomicAdd(&deg[col[i]], 1);
}

// ---------------- dinv ----------------
__global__ void dinv_kernel(const int* __restrict__ deg, float* __restrict__ dinv, int N) {
    int i = blockIdx.x * blockDim.x + threadIdx.x;
    if (i < N) {
        int d = deg[i];
        dinv[i] = (d > 0) ? (1.0f / sqrtf((float)d)) : 1.0f;
    }
}

// ---------------- scan (3 kernels) ----------------
__global__ void scan1(const int* __restrict__ deg, int* __restrict__ rowptr,
                      int* __restrict__ bsum, int N) {
    __shared__ int tmp[1024];
    int t = threadIdx.x;
    int gid = blockIdx.x * 1024 + t;
    int v = (gid < N) ? deg[gid] : 0;
    tmp[t] = v;
    __syncthreads();
    for (int off = 1; off < 1024; off <<= 1) {
        int u = (t >= off) ? tmp[t - off] : 0;
        __syncthreads();
        tmp[t] += u;
        __syncthreads();
    }
    if (gid < N) rowptr[gid] = tmp[t] - v;   // exclusive within block
    if (t == 1023) bsum[blockIdx.x] = tmp[1023];
}

__global__ void scan2(int* __restrict__ bs, int nb) {
    __shared__ int tmp[1024];
    int t = threadIdx.x;
    int v = (t < nb) ? bs[t] : 0;
    tmp[t] = v;
    __syncthreads();
    for (int off = 1; off < 1024; off <<= 1) {
        int u = (t >= off) ? tmp[t - off] : 0;
        __syncthreads();
        tmp[t] += u;
        __syncthreads();
    }
    if (t < nb) bs[t] = tmp[t] - v;          // exclusive
}

__global__ void scan3(int* __restrict__ rowptr, const int* __restrict__ bs, int E, int N) {
    int gid = blockIdx.x * 1024 + threadIdx.x;
    if (gid < N) rowptr[gid] += bs[blockIdx.x];
    if (gid == 0) rowptr[N] = E;
}

// ---------------- CSR scatter: edges[pos] = (src, norm_bits) ----------------
__global__ void scatter_kernel(const int* __restrict__ row, const int* __restrict__ col,
                               const float* __restrict__ dinv, const int* __restrict__ rowptr,
                               int* __restrict__ cnt, int2* __restrict__ edges, int E) {
    int i = blockIdx.x * blockDim.x + threadIdx.x;
    if (i >= E) return;
    int r = row[i];
    int c = col[i];
    int pos = rowptr[c] + atomicAdd(&cnt[c], 1);
    edges[pos] = make_int2(r, __float_as_int(dinv[r] * dinv[c]));
}

// ---------------- tiled GEMM: h = x@W + b ; ret = h * mf[0][c] ----------------
// block: 256 threads, tile 128 rows x 64 cols, thread computes 8x4 outputs.
__global__ void gemm_kernel(const float4* __restrict__ x4, const float4* __restrict__ W4,
                            const float4* __restrict__ b4, const float4* __restrict__ mf4,
                            float4* __restrict__ h4, float4* __restrict__ ret4, int N) {
    __shared__ float xs[16 * 128];          // [k][row] transposed, 8 KB
    __shared__ float4 Ws4[16 * 16];         // [k][c4], 4 KB
    const int t = threadIdx.x;
    const int tx = t & 15;                  // col quad: cols tx*4..+4
    const int ty = t >> 4;                  // row octet: rows ty*8..+8
    const int rowblk = blockIdx.x * 128;

    float4 bb = b4[tx];
    float4 acc[8];
    #pragma unroll
    for (int i = 0; i < 8; ++i) acc[i] = bb;

    for (int kc = 0; kc < F_IN; kc += 16) {
        // stage x tile (transposed)
        #pragma unroll
        for (int ii = 0; ii < 2; ++ii) {
            int i = t + ii * 256;           // 0..511
            int r = i >> 2;                 // 0..127
            int q = i & 3;                  // float4 within k-chunk
            int gr = rowblk + r;
            float4 v = make_float4(0.f, 0.f, 0.f, 0.f);
            if (gr < N) v = x4[(size_t)gr * (F_IN / 4) + (kc >> 2) + q];
            int kb = q * 4;
            xs[(kb + 0) * 128 + r] = v.x;
            xs[(kb + 1) * 128 + r] = v.y;
            xs[(kb + 2) * 128 + r] = v.z;
            xs[(kb + 3) * 128 + r] = v.w;
        }
        // stage W tile
        Ws4[ty * 16 + tx] = W4[(size_t)(kc + ty) * 16 + tx];
        __syncthreads();
        #pragma unroll
        for (int kk = 0; kk < 16; ++kk) {
            float4 a0 = *(const float4*)&xs[kk * 128 + ty * 8];
            float4 a1 = *(const float4*)&xs[kk * 128 + ty * 8 + 4];
            float4 bv = Ws4[kk * 16 + tx];
            float a[8] = {a0.x, a0.y, a0.z, a0.w, a1.x, a1.y, a1.z, a1.w};
            #pragma unroll
            for (int i = 0; i < 8; ++i) {
                acc[i].x = fmaf(a[i], bv.x, acc[i].x);
                acc[i].y = fmaf(a[i], bv.y, acc[i].y);
                acc[i].z = fmaf(a[i], bv.z, acc[i].z);
                acc[i].w = fmaf(a[i], bv.w, acc[i].w);
            }
        }
        __syncthreads();
    }
    float4 m0 = mf4[tx];
    #pragma unroll
    for (int i = 0; i < 8; ++i) {
        int gr = rowblk + ty * 8 + i;
        if (gr < N) {
            size_t idx = (size_t)gr * 16 + tx;
            h4[idx] = acc[i];
            float4 r;
            r.x = acc[i].x * m0.x; r.y = acc[i].y * m0.y;
            r.z = acc[i].z * m0.z; r.w = acc[i].w * m0.w;
            ret4[idx] = r;
        }
    }
}

// ---------------- propagation + polynomial accumulate ----------------
// 16 lanes per node, float4 per lane = full 64-channel row per gather.
// mode 0: P1 = prop(Hin);  mode 1: Pn = 2*prop(Hin) - Pout(old)
__global__ void prop_kernel(const int* __restrict__ rowptr, const int2* __restrict__ edges,
                            const float4* __restrict__ Hin, float4* __restrict__ Pout,
                            float4* __restrict__ ret, const float* __restrict__ lap,
                            const float4* __restrict__ mf4, int k, int mode, int N) {
    int gtid = blockIdx.x * blockDim.x + threadIdx.x;
    int node = gtid >> 4;
    int lc = gtid & 15;
    if (node >= N) return;
    int beg = rowptr[node];
    int end = rowptr[node + 1];
    float4 acc = make_float4(0.f, 0.f, 0.f, 0.f);
    for (int e = beg; e < end; ++e) {
        int2 ed = edges[e];
        float w = __int_as_float(ed.y);
        float4 hv = Hin[(size_t)ed.x * 16 + lc];
        acc.x = fmaf(w, hv.x, acc.x);
        acc.y = fmaf(w, hv.y, acc.y);
        acc.z = fmaf(w, hv.z, acc.z);
        acc.w = fmaf(w, hv.w, acc.w);
    }
    size_t idx = (size_t)node * 16 + lc;
    float4 p;
    if (mode == 0) {
        p = acc;
    } else {
        float4 old = Pout[idx];
        p.x = 2.0f * acc.x - old.x;
        p.y = 2.0f * acc.y - old.y;
        p.z = 2.0f * acc.z - old.z;
        p.w = 2.0f * acc.w - old.w;
    }
    Pout[idx] = p;
    float lw = lap[k - 1];
    float4 m = mf4[k * 16 + lc];
    float4 r = ret[idx];
    r.x = fmaf(lw * m.x, p.x, r.x);
    r.y = fmaf(lw * m.y, p.y, r.y);
    r.z = fmaf(lw * m.z, p.z, r.z);
    r.w = fmaf(lw * m.w, p.w, r.w);
    ret[idx] = r;
}

// ---------------- log softmax (wave per row) ----------------
__global__ void lsm_kernel(float* __restrict__ ret, int N) {
    int wid = (blockIdx.x * blockDim.x + threadIdx.x) >> 6;
    int c = threadIdx.x & 63;
    if (wid >= N) return;
    size_t idx = (size_t)wid * C_DIM + c;
    float v = ret[idx];
    float m = v;
    for (int off = 32; off; off >>= 1) m = fmaxf(m, __shfl_xor(m, off, 64));
    float ex = __expf(v - m);
    float s = ex;
    for (int off = 32; off; off >>= 1) s += __shfl_xor(s, off, 64);
    ret[idx] = (v - m) - logf(s);
}

extern "C" void kernel_launch(void* const* d_in, const int* in_sizes, int n_in,
                              void* d_out, int out_size, void* d_ws, size_t ws_size,
                              hipStream_t stream) {
    const float* x   = (const float*)d_in[0];
    const int*   ei  = (const int*)d_in[1];
    const float* W   = (const float*)d_in[2];
    const float* b   = (const float*)d_in[3];
    const float* lap = (const float*)d_in[4];
    const float* mf  = (const float*)d_in[5];
    float* ret = (float*)d_out;

    const int C = in_sizes[3];            // 64
    const int FIN = in_sizes[2] / C;      // 512
    const int N = in_sizes[0] / FIN;      // 100000
    const int E = in_sizes[1] / 2;        // 3200000
    const int K = in_sizes[4] - 1;        // 10
    const int* rowi = ei;                 // edge_index[0]
    const int* coli = ei + E;             // edge_index[1]

    // workspace layout (256B aligned)
    char* w = (char*)d_ws;
    auto alloc = [&](size_t bytes) {
        void* p = (void*)w;
        w += (bytes + 255) & ~(size_t)255;
        return p;
    };
    int*   deg    = (int*)alloc((size_t)N * 4);
    int*   cnt    = (int*)alloc((size_t)N * 4);
    int*   rowptr = (int*)alloc((size_t)(N + 1) * 4);
    int*   bsum   = (int*)alloc(4096);
    float* dinv   = (float*)alloc((size_t)N * 4);
    int2*  edges  = (int2*)alloc((size_t)E * 8);
    float* h      = (float*)alloc((size_t)N * C_DIM * 4);
    float* pbuf   = (float*)alloc((size_t)N * C_DIM * 4);

    hipMemsetAsync(deg, 0, (size_t)N * 4, stream);
    hipMemsetAsync(cnt, 0, (size_t)N * 4, stream);

    deg_kernel<<<(E + 255) / 256, 256, 0, stream>>>(coli, deg, E);
    dinv_kernel<<<(N + 255) / 256, 256, 0, stream>>>(deg, dinv, N);

    int nb = (N + 1023) / 1024;
    scan1<<<nb, 1024, 0, stream>>>(deg, rowptr, bsum, N);
    scan2<<<1, 1024, 0, stream>>>(bsum, nb);
    scan3<<<nb, 1024, 0, stream>>>(rowptr, bsum, E, N);

    scatter_kernel<<<(E + 255) / 256, 256, 0, stream>>>(rowi, coli, dinv, rowptr, cnt,
                                                        edges, E);

    gemm_kernel<<<(N + 127) / 128, 256, 0, stream>>>(
        (const float4*)x, (const float4*)W, (const float4*)b, (const float4*)mf,
        (float4*)h, (float4*)ret, N);

    // P0 = h (in ret already). P1 = prop(h) into pbuf.
    float* prev2 = h;
    float* prev1 = pbuf;
    int pgrid = ((size_t)N * 16 + 255) / 256;
    prop_kernel<<<pgrid, 256, 0, stream>>>(rowptr, edges, (const float4*)h, (float4*)pbuf,
                                           (float4*)ret, lap, (const float4*)mf, 1, 0, N);
    for (int k = 2; k <= K; ++k) {
        prop_kernel<<<pgrid, 256, 0, stream>>>(rowptr, edges, (const float4*)prev1,
                                               (float4*)prev2, (float4*)ret, lap,
                                               (const float4*)mf, k, 1, N);
        float* t = prev2;   // now holds P_k
        prev2 = prev1;
        prev1 = t;
    }

    lsm_kernel<<<((size_t)N * 64 + 255) / 256, 256, 0, stream>>>(ret, N);
}

// Round 3
// 1869.720 us; speedup vs baseline: 2.0516x; 1.0656x over previous
//
#include <hip/hip_runtime.h>
#include <hip/hip_bf16.h>

#define F_IN 512
#define C_DIM 64
#define BUCKET_BITS 9          // 512 nodes per bucket
#define EPB 2048               // edges per block in bucket_scatter

// ---------------- degree histogram (int4 reads) ----------------
__global__ void deg_kernel(const int* __restrict__ col, int* __restrict__ deg, int E) {
    int i = blockIdx.x * blockDim.x + threadIdx.x;
    int e = i * 4;
    if (e + 3 < E) {
        int4 c4 = *(const int4*)(col + e);
        atomicAdd(&deg[c4.x], 1);
        atomicAdd(&deg[c4.y], 1);
        atomicAdd(&deg[c4.z], 1);
        atomicAdd(&deg[c4.w], 1);
    } else if (e < E) {
        for (int j = e; j < E; ++j) atomicAdd(&deg[col[j]], 1);
    }
}

// ---------------- dinv ----------------
__global__ void dinv_kernel(const int* __restrict__ deg, float* __restrict__ dinv, int N) {
    int i = blockIdx.x * blockDim.x + threadIdx.x;
    if (i < N) {
        int d = deg[i];
        dinv[i] = (d > 0) ? (1.0f / sqrtf((float)d)) : 1.0f;
    }
}

// ---------------- scan (3 kernels) ----------------
__global__ void scan1(const int* __restrict__ deg, int* __restrict__ rowptr,
                      int* __restrict__ bsum, int N) {
    __shared__ int tmp[1024];
    int t = threadIdx.x;
    int gid = blockIdx.x * 1024 + t;
    int v = (gid < N) ? deg[gid] : 0;
    tmp[t] = v;
    __syncthreads();
    for (int off = 1; off < 1024; off <<= 1) {
        int u = (t >= off) ? tmp[t - off] : 0;
        __syncthreads();
        tmp[t] += u;
        __syncthreads();
    }
    if (gid < N) rowptr[gid] = tmp[t] - v;   // exclusive within block
    if (t == 1023) bsum[blockIdx.x] = tmp[1023];
}

__global__ void scan2(int* __restrict__ bs, int nb) {
    __shared__ int tmp[1024];
    int t = threadIdx.x;
    int v = (t < nb) ? bs[t] : 0;
    tmp[t] = v;
    __syncthreads();
    for (int off = 1; off < 1024; off <<= 1) {
        int u = (t >= off) ? tmp[t - off] : 0;
        __syncthreads();
        tmp[t] += u;
        __syncthreads();
    }
    if (t < nb) bs[t] = tmp[t] - v;          // exclusive
}

__global__ void scan3(int* __restrict__ rowptr, const int* __restrict__ bs, int E, int N) {
    int gid = blockIdx.x * 1024 + threadIdx.x;
    if (gid < N) rowptr[gid] += bs[blockIdx.x];
    if (gid == 0) rowptr[N] = E;
}

// ---------------- bucket pointers: bucketptr[b] = rowptr[min(b*512, N)] ----------------
__global__ void bucketptr_kernel(const int* __restrict__ rowptr, int* __restrict__ bucketptr,
                                 int N, int NB) {
    int b = blockIdx.x * blockDim.x + threadIdx.x;
    if (b <= NB) {
        int idx = b << BUCKET_BITS;
        if (idx > N) idx = N;
        bucketptr[b] = rowptr[idx];
    }
}

// ---------------- pass B: bucket-grouped compact append ----------------
__global__ void bucket_scatter(const int* __restrict__ row, const int* __restrict__ col,
                               const float* __restrict__ dinv,
                               const int* __restrict__ bucketptr, int* __restrict__ bcnt,
                               int2* __restrict__ staged, int* __restrict__ staged_dst, int E) {
    __shared__ int lcnt[256];
    __shared__ int lbase[256];
    int t = threadIdx.x;
    lcnt[t] = 0;
    __syncthreads();
    int base_e = blockIdx.x * EPB;
    int rr[8], cc[8], pk[8];
    #pragma unroll
    for (int j = 0; j < 8; ++j) {
        int e = base_e + j * 256 + t;
        pk[j] = -1;
        if (e < E) {
            rr[j] = row[e];
            cc[j] = col[e];
            int b = cc[j] >> BUCKET_BITS;
            int off = atomicAdd(&lcnt[b], 1);
            pk[j] = off | (b << 20);
        }
    }
    __syncthreads();
    lbase[t] = atomicAdd(&bcnt[t], lcnt[t]);
    __syncthreads();
    #pragma unroll
    for (int j = 0; j < 8; ++j) {
        if (pk[j] >= 0) {
            int b = pk[j] >> 20;
            int off = pk[j] & 0xFFFFF;
            int pos = bucketptr[b] + lbase[b] + off;
            staged[pos] = make_int2(rr[j], __float_as_int(dinv[rr[j]] * dinv[cc[j]]));
            staged_dst[pos] = cc[j];
        }
    }
}

// ---------------- pass C: final in-bucket scatter (L2-local writes) ----------------
__global__ void final_scatter(const int2* __restrict__ staged, const int* __restrict__ staged_dst,
                              const int* __restrict__ rowptr, int* __restrict__ cnt,
                              int2* __restrict__ edges, int E) {
    int i = blockIdx.x * blockDim.x + threadIdx.x;
    if (i >= E) return;
    int c = staged_dst[i];
    int pos = rowptr[c] + atomicAdd(&cnt[c], 1);
    edges[pos] = staged[i];
}

// ---------------- tiled GEMM: h = x@W + b ; ret = h * mf[0][c] ----------------
__global__ void gemm_kernel(const float4* __restrict__ x4, const float4* __restrict__ W4,
                            const float4* __restrict__ b4, const float4* __restrict__ mf4,
                            float4* __restrict__ h4, float4* __restrict__ ret4, int N) {
    __shared__ float xs[16 * 128];          // [k][row] transposed, 8 KB
    __shared__ float4 Ws4[16 * 16];         // [k][c4], 4 KB
    const int t = threadIdx.x;
    const int tx = t & 15;                  // col quad: cols tx*4..+4
    const int ty = t >> 4;                  // row octet: rows ty*8..+8
    const int rowblk = blockIdx.x * 128;

    float4 bb = b4[tx];
    float4 acc[8];
    #pragma unroll
    for (int i = 0; i < 8; ++i) acc[i] = bb;

    for (int kc = 0; kc < F_IN; kc += 16) {
        #pragma unroll
        for (int ii = 0; ii < 2; ++ii) {
            int i = t + ii * 256;           // 0..511
            int r = i >> 2;                 // 0..127
            int q = i & 3;
            int gr = rowblk + r;
            float4 v = make_float4(0.f, 0.f, 0.f, 0.f);
            if (gr < N) v = x4[(size_t)gr * (F_IN / 4) + (kc >> 2) + q];
            int kb = q * 4;
            xs[(kb + 0) * 128 + r] = v.x;
            xs[(kb + 1) * 128 + r] = v.y;
            xs[(kb + 2) * 128 + r] = v.z;
            xs[(kb + 3) * 128 + r] = v.w;
        }
        Ws4[ty * 16 + tx] = W4[(size_t)(kc + ty) * 16 + tx];
        __syncthreads();
        #pragma unroll
        for (int kk = 0; kk < 16; ++kk) {
            float4 a0 = *(const float4*)&xs[kk * 128 + ty * 8];
            float4 a1 = *(const float4*)&xs[kk * 128 + ty * 8 + 4];
            float4 bv = Ws4[kk * 16 + tx];
            float a[8] = {a0.x, a0.y, a0.z, a0.w, a1.x, a1.y, a1.z, a1.w};
            #pragma unroll
            for (int i = 0; i < 8; ++i) {
                acc[i].x = fmaf(a[i], bv.x, acc[i].x);
                acc[i].y = fmaf(a[i], bv.y, acc[i].y);
                acc[i].z = fmaf(a[i], bv.z, acc[i].z);
                acc[i].w = fmaf(a[i], bv.w, acc[i].w);
            }
        }
        __syncthreads();
    }
    float4 m0 = mf4[tx];
    #pragma unroll
    for (int i = 0; i < 8; ++i) {
        int gr = rowblk + ty * 8 + i;
        if (gr < N) {
            size_t idx = (size_t)gr * 16 + tx;
            h4[idx] = acc[i];
            float4 r;
            r.x = acc[i].x * m0.x; r.y = acc[i].y * m0.y;
            r.z = acc[i].z * m0.z; r.w = acc[i].w * m0.w;
            ret4[idx] = r;
        }
    }
}

// ---------------- propagation + polynomial accumulate (unroll x4) ----------------
// 16 lanes per node, float4 per lane = full 64-channel row per gather.
// mode 0: P1 = prop(Hin);  mode 1: Pn = 2*prop(Hin) - Pout(old)
__global__ void prop_kernel(const int* __restrict__ rowptr, const int2* __restrict__ edges,
                            const float4* __restrict__ Hin, float4* __restrict__ Pout,
                            float4* __restrict__ ret, const float* __restrict__ lap,
                            const float4* __restrict__ mf4, int k, int mode, int N) {
    int gtid = blockIdx.x * blockDim.x + threadIdx.x;
    int node = gtid >> 4;
    int lc = gtid & 15;
    if (node >= N) return;
    int beg = rowptr[node];
    int end = rowptr[node + 1];
    float4 a0 = make_float4(0.f, 0.f, 0.f, 0.f);
    float4 a1 = a0, a2 = a0, a3 = a0;
    int e = beg;
    for (; e + 4 <= end; e += 4) {
        int2 d0 = edges[e + 0];
        int2 d1 = edges[e + 1];
        int2 d2 = edges[e + 2];
        int2 d3 = edges[e + 3];
        float4 h0 = Hin[(size_t)d0.x * 16 + lc];
        float4 h1 = Hin[(size_t)d1.x * 16 + lc];
        float4 h2 = Hin[(size_t)d2.x * 16 + lc];
        float4 h3 = Hin[(size_t)d3.x * 16 + lc];
        float w0 = __int_as_float(d0.y), w1 = __int_as_float(d1.y);
        float w2 = __int_as_float(d2.y), w3 = __int_as_float(d3.y);
        a0.x = fmaf(w0, h0.x, a0.x); a0.y = fmaf(w0, h0.y, a0.y);
        a0.z = fmaf(w0, h0.z, a0.z); a0.w = fmaf(w0, h0.w, a0.w);
        a1.x = fmaf(w1, h1.x, a1.x); a1.y = fmaf(w1, h1.y, a1.y);
        a1.z = fmaf(w1, h1.z, a1.z); a1.w = fmaf(w1, h1.w, a1.w);
        a2.x = fmaf(w2, h2.x, a2.x); a2.y = fmaf(w2, h2.y, a2.y);
        a2.z = fmaf(w2, h2.z, a2.z); a2.w = fmaf(w2, h2.w, a2.w);
        a3.x = fmaf(w3, h3.x, a3.x); a3.y = fmaf(w3, h3.y, a3.y);
        a3.z = fmaf(w3, h3.z, a3.z); a3.w = fmaf(w3, h3.w, a3.w);
    }
    for (; e < end; ++e) {
        int2 d = edges[e];
        float w = __int_as_float(d.y);
        float4 hv = Hin[(size_t)d.x * 16 + lc];
        a0.x = fmaf(w, hv.x, a0.x); a0.y = fmaf(w, hv.y, a0.y);
        a0.z = fmaf(w, hv.z, a0.z); a0.w = fmaf(w, hv.w, a0.w);
    }
    float4 acc;
    acc.x = (a0.x + a1.x) + (a2.x + a3.x);
    acc.y = (a0.y + a1.y) + (a2.y + a3.y);
    acc.z = (a0.z + a1.z) + (a2.z + a3.z);
    acc.w = (a0.w + a1.w) + (a2.w + a3.w);

    size_t idx = (size_t)node * 16 + lc;
    float4 p;
    if (mode == 0) {
        p = acc;
    } else {
        float4 old = Pout[idx];
        p.x = 2.0f * acc.x - old.x;
        p.y = 2.0f * acc.y - old.y;
        p.z = 2.0f * acc.z - old.z;
        p.w = 2.0f * acc.w - old.w;
    }
    Pout[idx] = p;
    float lw = lap[k - 1];
    float4 m = mf4[k * 16 + lc];
    float4 r = ret[idx];
    r.x = fmaf(lw * m.x, p.x, r.x);
    r.y = fmaf(lw * m.y, p.y, r.y);
    r.z = fmaf(lw * m.z, p.z, r.z);
    r.w = fmaf(lw * m.w, p.w, r.w);
    ret[idx] = r;
}

// ---------------- log softmax (wave per row) ----------------
__global__ void lsm_kernel(float* __restrict__ ret, int N) {
    int wid = (blockIdx.x * blockDim.x + threadIdx.x) >> 6;
    int c = threadIdx.x & 63;
    if (wid >= N) return;
    size_t idx = (size_t)wid * C_DIM + c;
    float v = ret[idx];
    float m = v;
    for (int off = 32; off; off >>= 1) m = fmaxf(m, __shfl_xor(m, off, 64));
    float ex = __expf(v - m);
    float s = ex;
    for (int off = 32; off; off >>= 1) s += __shfl_xor(s, off, 64);
    ret[idx] = (v - m) - logf(s);
}

extern "C" void kernel_launch(void* const* d_in, const int* in_sizes, int n_in,
                              void* d_out, int out_size, void* d_ws, size_t ws_size,
                              hipStream_t stream) {
    const float* x   = (const float*)d_in[0];
    const int*   ei  = (const int*)d_in[1];
    const float* W   = (const float*)d_in[2];
    const float* b   = (const float*)d_in[3];
    const float* lap = (const float*)d_in[4];
    const float* mf  = (const float*)d_in[5];
    float* ret = (float*)d_out;

    const int C = in_sizes[3];            // 64
    const int FIN = in_sizes[2] / C;      // 512
    const int N = in_sizes[0] / FIN;      // 100000
    const int E = in_sizes[1] / 2;        // 3200000
    const int K = in_sizes[4] - 1;        // 10
    const int* rowi = ei;                 // edge_index[0]
    const int* coli = ei + E;             // edge_index[1]
    const int NB = (N + (1 << BUCKET_BITS) - 1) >> BUCKET_BITS;   // <= 256

    // workspace layout (256B aligned)
    char* w = (char*)d_ws;
    auto alloc = [&](size_t bytes) {
        void* p = (void*)w;
        w += (bytes + 255) & ~(size_t)255;
        return p;
    };
    int*   deg    = (int*)alloc((size_t)N * 4);
    int*   cnt    = (int*)alloc((size_t)N * 4);
    int*   rowptr = (int*)alloc((size_t)(N + 1) * 4);
    int*   bsum   = (int*)alloc(4096);
    float* dinv   = (float*)alloc((size_t)N * 4);
    int*   bcnt   = (int*)alloc(256 * 4);
    int*   bucketptr = (int*)alloc(4096);
    int2*  edges  = (int2*)alloc((size_t)E * 8);
    float* h      = (float*)alloc((size_t)N * C_DIM * 4);
    float* pbuf   = (float*)alloc((size_t)N * C_DIM * 4);
    // staged arrays alias h/pbuf (dead until gemm; build completes first)
    int2*  staged     = (int2*)h;          // E*8 = 25.6 MB <= N*64*4
    int*   staged_dst = (int*)pbuf;        // E*4 = 12.8 MB

    hipMemsetAsync(deg, 0, (size_t)N * 4, stream);
    hipMemsetAsync(cnt, 0, (size_t)N * 4, stream);
    hipMemsetAsync(bcnt, 0, 256 * 4, stream);

    deg_kernel<<<((E + 3) / 4 + 255) / 256, 256, 0, stream>>>(coli, deg, E);
    dinv_kernel<<<(N + 255) / 256, 256, 0, stream>>>(deg, dinv, N);

    int nb = (N + 1023) / 1024;
    scan1<<<nb, 1024, 0, stream>>>(deg, rowptr, bsum, N);
    scan2<<<1, 1024, 0, stream>>>(bsum, nb);
    scan3<<<nb, 1024, 0, stream>>>(rowptr, bsum, E, N);
    bucketptr_kernel<<<(NB + 1 + 255) / 256, 256, 0, stream>>>(rowptr, bucketptr, N, NB);

    bucket_scatter<<<(E + EPB - 1) / EPB, 256, 0, stream>>>(rowi, coli, dinv, bucketptr,
                                                            bcnt, staged, staged_dst, E);
    final_scatter<<<(E + 255) / 256, 256, 0, stream>>>(staged, staged_dst, rowptr, cnt,
                                                       edges, E);

    gemm_kernel<<<(N + 127) / 128, 256, 0, stream>>>(
        (const float4*)x, (const float4*)W, (const float4*)b, (const float4*)mf,
        (float4*)h, (float4*)ret, N);

    // P0 = h (in ret already). P1 = prop(h) into pbuf.
    float* prev2 = h;
    float* prev1 = pbuf;
    int pgrid = ((size_t)N * 16 + 255) / 256;
    prop_kernel<<<pgrid, 256, 0, stream>>>(rowptr, edges, (const float4*)h, (float4*)pbuf,
                                           (float4*)ret, lap, (const float4*)mf, 1, 0, N);
    for (int k = 2; k <= K; ++k) {
        prop_kernel<<<pgrid, 256, 0, stream>>>(rowptr, edges, (const float4*)prev1,
                                               (float4*)prev2, (float4*)ret, lap,
                                               (const float4*)mf, k, 1, N);
        float* t = prev2;   // now holds P_k
        prev2 = prev1;
        prev1 = t;
    }

    lsm_kernel<<<((size_t)N * 64 + 255) / 256, 256, 0, stream>>>(ret, N);
}

// Round 4
// 1344.133 us; speedup vs baseline: 2.8538x; 1.3910x over previous
//
#include <hip/hip_runtime.h>
#include <hip/hip_bf16.h>

#define F_IN 512
#define C_DIM 64
#define BUCKET_BITS 9          // 512 nodes per bucket
#define EPB 2048               // edges per block in bucket_scatter
#define XR 36                  // LDS x row stride (floats)
#define WR 36                  // LDS wt col stride (floats)

// ---------------- degree histogram (int4 reads) ----------------
__global__ void deg_kernel(const int* __restrict__ col, int* __restrict__ deg, int E) {
    int i = blockIdx.x * blockDim.x + threadIdx.x;
    int e = i * 4;
    if (e + 3 < E) {
        int4 c4 = *(const int4*)(col + e);
        atomicAdd(&deg[c4.x], 1);
        atomicAdd(&deg[c4.y], 1);
        atomicAdd(&deg[c4.z], 1);
        atomicAdd(&deg[c4.w], 1);
    } else if (e < E) {
        for (int j = e; j < E; ++j) atomicAdd(&deg[col[j]], 1);
    }
}

// ---------------- dinv ----------------
__global__ void dinv_kernel(const int* __restrict__ deg, float* __restrict__ dinv, int N) {
    int i = blockIdx.x * blockDim.x + threadIdx.x;
    if (i < N) {
        int d = deg[i];
        dinv[i] = (d > 0) ? (1.0f / sqrtf((float)d)) : 1.0f;
    }
}

// ---------------- scan (3 kernels) ----------------
__global__ void scan1(const int* __restrict__ deg, int* __restrict__ rowptr,
                      int* __restrict__ bsum, int N) {
    __shared__ int tmp[1024];
    int t = threadIdx.x;
    int gid = blockIdx.x * 1024 + t;
    int v = (gid < N) ? deg[gid] : 0;
    tmp[t] = v;
    __syncthreads();
    for (int off = 1; off < 1024; off <<= 1) {
        int u = (t >= off) ? tmp[t - off] : 0;
        __syncthreads();
        tmp[t] += u;
        __syncthreads();
    }
    if (gid < N) rowptr[gid] = tmp[t] - v;
    if (t == 1023) bsum[blockIdx.x] = tmp[1023];
}

__global__ void scan2(int* __restrict__ bs, int nb) {
    __shared__ int tmp[1024];
    int t = threadIdx.x;
    int v = (t < nb) ? bs[t] : 0;
    tmp[t] = v;
    __syncthreads();
    for (int off = 1; off < 1024; off <<= 1) {
        int u = (t >= off) ? tmp[t - off] : 0;
        __syncthreads();
        tmp[t] += u;
        __syncthreads();
    }
    if (t < nb) bs[t] = tmp[t] - v;
}

__global__ void scan3(int* __restrict__ rowptr, const int* __restrict__ bs, int E, int N) {
    int gid = blockIdx.x * 1024 + threadIdx.x;
    if (gid < N) rowptr[gid] += bs[blockIdx.x];
    if (gid == 0) rowptr[N] = E;
}

// ---------------- bucket pointers ----------------
__global__ void bucketptr_kernel(const int* __restrict__ rowptr, int* __restrict__ bucketptr,
                                 int N, int NB) {
    int b = blockIdx.x * blockDim.x + threadIdx.x;
    if (b <= NB) {
        int idx = b << BUCKET_BITS;
        if (idx > N) idx = N;
        bucketptr[b] = rowptr[idx];
    }
}

// ---------------- pass B: bucket-grouped compact append ----------------
__global__ void bucket_scatter(const int* __restrict__ row, const int* __restrict__ col,
                               const float* __restrict__ dinv,
                               const int* __restrict__ bucketptr, int* __restrict__ bcnt,
                               int2* __restrict__ staged, int* __restrict__ staged_dst, int E) {
    __shared__ int lcnt[256];
    __shared__ int lbase[256];
    int t = threadIdx.x;
    lcnt[t] = 0;
    __syncthreads();
    int base_e = blockIdx.x * EPB;
    int rr[8], cc[8], pk[8];
    #pragma unroll
    for (int j = 0; j < 8; ++j) {
        int e = base_e + j * 256 + t;
        pk[j] = -1;
        if (e < E) {
            rr[j] = row[e];
            cc[j] = col[e];
            int b = cc[j] >> BUCKET_BITS;
            int off = atomicAdd(&lcnt[b], 1);
            pk[j] = off | (b << 20);
        }
    }
    __syncthreads();
    lbase[t] = atomicAdd(&bcnt[t], lcnt[t]);
    __syncthreads();
    #pragma unroll
    for (int j = 0; j < 8; ++j) {
        if (pk[j] >= 0) {
            int b = pk[j] >> 20;
            int off = pk[j] & 0xFFFFF;
            int pos = bucketptr[b] + lbase[b] + off;
            staged[pos] = make_int2(rr[j], __float_as_int(dinv[rr[j]] * dinv[cc[j]]));
            staged_dst[pos] = cc[j];
        }
    }
}

// ---------------- pass C: final in-bucket scatter ----------------
__global__ void final_scatter(const int2* __restrict__ staged, const int* __restrict__ staged_dst,
                              const int* __restrict__ rowptr, int* __restrict__ cnt,
                              int2* __restrict__ edges, int E) {
    int i = blockIdx.x * blockDim.x + threadIdx.x;
    if (i >= E) return;
    int c = staged_dst[i];
    int pos = rowptr[c] + atomicAdd(&cnt[c], 1);
    edges[pos] = staged[i];
}

// ---------------- tiled GEMM v3: 64x64 tile, K-chunk 32, strided col map ----------------
__global__ void gemm_kernel(const float4* __restrict__ x4, const float4* __restrict__ W4,
                            const float* __restrict__ b, const float* __restrict__ mf,
                            float* __restrict__ h, float* __restrict__ ret, int N) {
    __shared__ float xs[64 * XR];    // 9216 B
    __shared__ float wt[64 * WR];    // 9216 B (W transposed: [col][k])
    const int t = threadIdx.x;
    const int tx = t & 15;           // cols tx + 16j
    const int ty = t >> 4;           // rows ty + 16i
    const int rowblk = blockIdx.x * 64;

    float acc[4][4];
    #pragma unroll
    for (int i = 0; i < 4; ++i)
        #pragma unroll
        for (int j = 0; j < 4; ++j) acc[i][j] = 0.f;

    for (int kc = 0; kc < F_IN; kc += 32) {
        #pragma unroll
        for (int ii = 0; ii < 2; ++ii) {
            int i = t + ii * 256;        // 0..511
            // x tile: 64 rows x 8 float4
            int r = i >> 3;
            int q = i & 7;
            int gr = rowblk + r;
            float4 v = make_float4(0.f, 0.f, 0.f, 0.f);
            if (gr < N) v = x4[(size_t)gr * (F_IN / 4) + (kc >> 2) + q];
            ((float4*)(xs + r * XR))[q] = v;
            // W tile transposed: 32 k x 64 c
            int k = i >> 4;              // 0..31
            int c4 = i & 15;
            float4 wv = W4[(size_t)(kc + k) * 16 + c4];
            wt[(4 * c4 + 0) * WR + k] = wv.x;
            wt[(4 * c4 + 1) * WR + k] = wv.y;
            wt[(4 * c4 + 2) * WR + k] = wv.z;
            wt[(4 * c4 + 3) * WR + k] = wv.w;
        }
        __syncthreads();
        #pragma unroll
        for (int kq = 0; kq < 8; ++kq) {
            float4 xr[4], wc[4];
            #pragma unroll
            for (int i = 0; i < 4; ++i)
                xr[i] = ((const float4*)(xs + (ty + 16 * i) * XR))[kq];
            #pragma unroll
            for (int j = 0; j < 4; ++j)
                wc[j] = ((const float4*)(wt + (tx + 16 * j) * WR))[kq];
            #pragma unroll
            for (int i = 0; i < 4; ++i)
                #pragma unroll
                for (int j = 0; j < 4; ++j) {
                    acc[i][j] = fmaf(xr[i].x, wc[j].x, acc[i][j]);
                    acc[i][j] = fmaf(xr[i].y, wc[j].y, acc[i][j]);
                    acc[i][j] = fmaf(xr[i].z, wc[j].z, acc[i][j]);
                    acc[i][j] = fmaf(xr[i].w, wc[j].w, acc[i][j]);
                }
        }
        __syncthreads();
    }
    float bb[4], mm[4];
    int cc[4];
    #pragma unroll
    for (int j = 0; j < 4; ++j) {
        cc[j] = tx + 16 * j;
        bb[j] = b[cc[j]];
        mm[j] = mf[cc[j]];
    }
    #pragma unroll
    for (int i = 0; i < 4; ++i) {
        int r = rowblk + ty + 16 * i;
        if (r < N) {
            #pragma unroll
            for (int j = 0; j < 4; ++j) {
                float v = acc[i][j] + bb[j];
                h[(size_t)r * C_DIM + cc[j]] = v;
                ret[(size_t)r * C_DIM + cc[j]] = v * mm[j];
            }
        }
    }
}

// ---------------- bf16 pack (RNE) ----------------
__device__ inline unsigned bfpack(float x, float y) {
    unsigned ux = __float_as_uint(x);
    ux += 0x7fffu + ((ux >> 16) & 1u);
    unsigned uy = __float_as_uint(y);
    uy += 0x7fffu + ((uy >> 16) & 1u);
    return (ux >> 16) | (uy & 0xffff0000u);
}

// ---------------- f32 -> bf16x2 conversion (h -> hb) ----------------
__global__ void conv_kernel(const float4* __restrict__ h4, uint4* __restrict__ hb, int n8) {
    int g = blockIdx.x * blockDim.x + threadIdx.x;
    if (g >= n8) return;
    float4 a = h4[2 * g];
    float4 c = h4[2 * g + 1];
    uint4 u;
    u.x = bfpack(a.x, a.y);
    u.y = bfpack(a.z, a.w);
    u.z = bfpack(c.x, c.y);
    u.w = bfpack(c.z, c.w);
    hb[g] = u;
}

// ---------------- propagation, bf16 state ----------------
// 8 lanes/node, each lane = 8 channels (one uint4 = 8 bf16).
// mode 0: P1 = prop(Hb);  mode 1: Pn = 2*prop(Hb) - unpack(Bold)
// Writes bf16(Pn) into Bold; accumulates lap*mf*Pn into ret (fp32).
__global__ void prop_kernel(const int* __restrict__ rowptr, const int2* __restrict__ edges,
                            const uint4* __restrict__ Hb, uint4* __restrict__ Bold,
                            float4* __restrict__ ret, const float* __restrict__ lap,
                            const float4* __restrict__ mf4, int k, int mode, int N) {
    int gtid = blockIdx.x * blockDim.x + threadIdx.x;
    int node = gtid >> 3;
    int lc = gtid & 7;
    if (node >= N) return;
    int beg = rowptr[node];
    int end = rowptr[node + 1];
    float a0 = 0.f, a1 = 0.f, a2 = 0.f, a3 = 0.f, a4 = 0.f, a5 = 0.f, a6 = 0.f, a7 = 0.f;

#define EDGE_FMA(SRC, WB) do { \
        float w_ = __int_as_float(WB); \
        uint4 u_ = Hb[(size_t)(SRC) * 8 + lc]; \
        a0 = fmaf(w_, __uint_as_float(u_.x << 16), a0); \
        a1 = fmaf(w_, __uint_as_float(u_.x & 0xffff0000u), a1); \
        a2 = fmaf(w_, __uint_as_float(u_.y << 16), a2); \
        a3 = fmaf(w_, __uint_as_float(u_.y & 0xffff0000u), a3); \
        a4 = fmaf(w_, __uint_as_float(u_.z << 16), a4); \
        a5 = fmaf(w_, __uint_as_float(u_.z & 0xffff0000u), a5); \
        a6 = fmaf(w_, __uint_as_float(u_.w << 16), a6); \
        a7 = fmaf(w_, __uint_as_float(u_.w & 0xffff0000u), a7); \
    } while (0)

    int e = beg;
    if ((e & 1) && e < end) {            // align to even for int4 pair loads
        int2 d = edges[e];
        EDGE_FMA(d.x, d.y);
        ++e;
    }
    for (; e + 4 <= end; e += 4) {
        int4 p0 = ((const int4*)edges)[e >> 1];
        int4 p1 = ((const int4*)edges)[(e >> 1) + 1];
        EDGE_FMA(p0.x, p0.y);
        EDGE_FMA(p0.z, p0.w);
        EDGE_FMA(p1.x, p1.y);
        EDGE_FMA(p1.z, p1.w);
    }
    for (; e < end; ++e) {
        int2 d = edges[e];
        EDGE_FMA(d.x, d.y);
    }
#undef EDGE_FMA

    size_t ib = (size_t)node * 8 + lc;
    float p0, p1, p2, p3, p4, p5, p6, p7;
    if (mode == 0) {
        p0 = a0; p1 = a1; p2 = a2; p3 = a3; p4 = a4; p5 = a5; p6 = a6; p7 = a7;
    } else {
        uint4 ob = Bold[ib];
        p0 = 2.f * a0 - __uint_as_float(ob.x << 16);
        p1 = 2.f * a1 - __uint_as_float(ob.x & 0xffff0000u);
        p2 = 2.f * a2 - __uint_as_float(ob.y << 16);
        p3 = 2.f * a3 - __uint_as_float(ob.y & 0xffff0000u);
        p4 = 2.f * a4 - __uint_as_float(ob.z << 16);
        p5 = 2.f * a5 - __uint_as_float(ob.z & 0xffff0000u);
        p6 = 2.f * a6 - __uint_as_float(ob.w << 16);
        p7 = 2.f * a7 - __uint_as_float(ob.w & 0xffff0000u);
    }
    uint4 nb;
    nb.x = bfpack(p0, p1);
    nb.y = bfpack(p2, p3);
    nb.z = bfpack(p4, p5);
    nb.w = bfpack(p6, p7);
    Bold[ib] = nb;

    float lw = lap[k - 1];
    size_t i16 = (size_t)node * 16 + lc * 2;
    float4 m0 = mf4[k * 16 + lc * 2];
    float4 m1 = mf4[k * 16 + lc * 2 + 1];
    float4 r0 = ret[i16];
    float4 r1 = ret[i16 + 1];
    r0.x = fmaf(lw * m0.x, p0, r0.x);
    r0.y = fmaf(lw * m0.y, p1, r0.y);
    r0.z = fmaf(lw * m0.z, p2, r0.z);
    r0.w = fmaf(lw * m0.w, p3, r0.w);
    r1.x = fmaf(lw * m1.x, p4, r1.x);
    r1.y = fmaf(lw * m1.y, p5, r1.y);
    r1.z = fmaf(lw * m1.z, p6, r1.z);
    r1.w = fmaf(lw * m1.w, p7, r1.w);
    ret[i16] = r0;
    ret[i16 + 1] = r1;
}

// ---------------- log softmax (wave per row) ----------------
__global__ void lsm_kernel(float* __restrict__ ret, int N) {
    int wid = (blockIdx.x * blockDim.x + threadIdx.x) >> 6;
    int c = threadIdx.x & 63;
    if (wid >= N) return;
    size_t idx = (size_t)wid * C_DIM + c;
    float v = ret[idx];
    float m = v;
    for (int off = 32; off; off >>= 1) m = fmaxf(m, __shfl_xor(m, off, 64));
    float ex = __expf(v - m);
    float s = ex;
    for (int off = 32; off; off >>= 1) s += __shfl_xor(s, off, 64);
    ret[idx] = (v - m) - logf(s);
}

extern "C" void kernel_launch(void* const* d_in, const int* in_sizes, int n_in,
                              void* d_out, int out_size, void* d_ws, size_t ws_size,
                              hipStream_t stream) {
    const float* x   = (const float*)d_in[0];
    const int*   ei  = (const int*)d_in[1];
    const float* W   = (const float*)d_in[2];
    const float* b   = (const float*)d_in[3];
    const float* lap = (const float*)d_in[4];
    const float* mf  = (const float*)d_in[5];
    float* ret = (float*)d_out;

    const int C = in_sizes[3];            // 64
    const int FIN = in_sizes[2] / C;      // 512
    const int N = in_sizes[0] / FIN;      // 100000
    const int E = in_sizes[1] / 2;        // 3200000
    const int K = in_sizes[4] - 1;        // 10
    const int* rowi = ei;
    const int* coli = ei + E;
    const int NB = (N + (1 << BUCKET_BITS) - 1) >> BUCKET_BITS;

    char* w = (char*)d_ws;
    auto alloc = [&](size_t bytes) {
        void* p = (void*)w;
        w += (bytes + 255) & ~(size_t)255;
        return p;
    };
    int*   deg    = (int*)alloc((size_t)N * 4);
    int*   cnt    = (int*)alloc((size_t)N * 4);
    int*   rowptr = (int*)alloc((size_t)(N + 1) * 4);
    int*   bsum   = (int*)alloc(4096);
    float* dinv   = (float*)alloc((size_t)N * 4);
    int*   bcnt   = (int*)alloc(256 * 4);
    int*   bucketptr = (int*)alloc(4096);
    int2*  edges  = (int2*)alloc((size_t)E * 8);
    float* h      = (float*)alloc((size_t)N * C_DIM * 4);    // fp32 h (P0 for ret, conv src)
    uint4* hb     = (uint4*)alloc((size_t)N * C_DIM * 2);    // bf16 state A
    uint4* pb     = (uint4*)alloc((size_t)N * C_DIM * 2);    // bf16 state B
    // staged arrays alias h + bf16 bufs (dead until gemm; build completes first)
    int2*  staged     = (int2*)h;       // E*8 = 25.6 MB <= h 25.6 MB
    int*   staged_dst = (int*)hb;       // E*4 = 12.8 MB <= hb 12.8 MB

    hipMemsetAsync(deg, 0, (size_t)N * 4, stream);
    hipMemsetAsync(cnt, 0, (size_t)N * 4, stream);
    hipMemsetAsync(bcnt, 0, 256 * 4, stream);

    deg_kernel<<<((E + 3) / 4 + 255) / 256, 256, 0, stream>>>(coli, deg, E);
    dinv_kernel<<<(N + 255) / 256, 256, 0, stream>>>(deg, dinv, N);

    int nb = (N + 1023) / 1024;
    scan1<<<nb, 1024, 0, stream>>>(deg, rowptr, bsum, N);
    scan2<<<1, 1024, 0, stream>>>(bsum, nb);
    scan3<<<nb, 1024, 0, stream>>>(rowptr, bsum, E, N);
    bucketptr_kernel<<<(NB + 1 + 255) / 256, 256, 0, stream>>>(rowptr, bucketptr, N, NB);

    bucket_scatter<<<(E + EPB - 1) / EPB, 256, 0, stream>>>(rowi, coli, dinv, bucketptr,
                                                            bcnt, staged, staged_dst, E);
    final_scatter<<<(E + 255) / 256, 256, 0, stream>>>(staged, staged_dst, rowptr, cnt,
                                                       edges, E);

    gemm_kernel<<<(N + 63) / 64, 256, 0, stream>>>(
        (const float4*)x, (const float4*)W, b, mf, h, ret, N);

    conv_kernel<<<(N * 8 + 255) / 256, 256, 0, stream>>>((const float4*)h, hb, N * 8);

    int pgrid = (N * 8 + 255) / 256;
    // P1 = prop(P0): gather hb, write pb
    prop_kernel<<<pgrid, 256, 0, stream>>>(rowptr, edges, hb, pb, (float4*)ret,
                                           lap, (const float4*)mf, 1, 0, N);
    uint4* gat = pb;   // holds P_{n-1}
    uint4* st  = hb;   // holds P_{n-2}, becomes P_n
    for (int k = 2; k <= K; ++k) {
        prop_kernel<<<pgrid, 256, 0, stream>>>(rowptr, edges, gat, st, (float4*)ret,
                                               lap, (const float4*)mf, k, 1, N);
        uint4* t2 = gat; gat = st; st = t2;
    }

    lsm_kernel<<<((size_t)N * 64 + 255) / 256, 256, 0, stream>>>(ret, N);
}